// Round 1
// baseline (436.416 us; speedup 1.0000x reference)
//
#include <hip/hip_runtime.h>
#include <math.h>

#define GNUM 16
#define CDIM 128
#define SLOT (GNUM*CDIM + 2*GNUM)   // 2080 floats per partial slot
#define NBMAX 1024

// ---------------- Kernel 1: normalize + per-block segment accumulate ----------------
// 256 threads = 4 waves. Each wave handles 2 rows per iteration:
//   lane loads float4 at pair-base + lane*16B  -> lanes 0-31 = row 2p, lanes 32-63 = row 2p+1.
// Per-wave private LDS accumulators (no cross-wave races); intra-wave collisions
// (both halves same group) handled by LDS float atomics (ds_add_f32).
__global__ __launch_bounds__(256, 4)
void oc_accum(const float* __restrict__ feat, const int* __restrict__ scores,
              float* __restrict__ partial, int B, int npairs)
{
    __shared__ float gsum[4][GNUM*CDIM];   // 32 KB
    __shared__ float gcnt[4][GNUM];
    __shared__ float gsq [4][GNUM];

    const int tid  = threadIdx.x;
    const int wave = tid >> 6;
    const int lane = tid & 63;
    const int hl   = lane & 31;       // lane within half-wave
    const int half = lane >> 5;       // which row of the pair
    const int q    = (hl >> 3) & 3;   // LDS bank-swizzle key

    for (int e = tid; e < 4*GNUM*CDIM; e += 256) (&gsum[0][0])[e] = 0.f;
    if (tid < 4*GNUM) { (&gcnt[0][0])[tid] = 0.f; (&gsq[0][0])[tid] = 0.f; }
    __syncthreads();

    const int gw = blockIdx.x*4 + wave;
    const int nw = gridDim.x*4;

    for (int p = gw; p < npairs; p += nw) {
        const int r = 2*p + half;
        float4 x = make_float4(0.f, 0.f, 0.f, 0.f);
        int g = 0;
        if (r < B) {
            x = *reinterpret_cast<const float4*>(feat + (size_t)p*(2*CDIM) + (size_t)lane*4);
            g = scores[r];
        }
        float ss = x.x*x.x + x.y*x.y + x.z*x.z + x.w*x.w;
        // reduce within the 32-lane half (masks < 32 never cross halves)
        ss += __shfl_xor(ss, 1);
        ss += __shfl_xor(ss, 2);
        ss += __shfl_xor(ss, 4);
        ss += __shfl_xor(ss, 8);
        ss += __shfl_xor(ss, 16);
        if (r < B) {
            const float inv = 1.0f / fmaxf(sqrtf(ss), 1e-12f);
            const float f0 = x.x*inv, f1 = x.y*inv, f2 = x.z*inv, f3 = x.w*inv;
            // position p gets value f_{p^q}  (static selection, no dynamic indexing)
            const float a0 = (q & 1) ? f1 : f0;
            const float a1 = (q & 1) ? f0 : f1;
            const float a2 = (q & 1) ? f3 : f2;
            const float a3 = (q & 1) ? f2 : f3;
            const float b0 = (q & 2) ? a2 : a0;
            const float b1 = (q & 2) ? a3 : a1;
            const float b2 = (q & 2) ? a0 : a2;
            const float b3 = (q & 2) ? a1 : a3;
            float* dst = &gsum[wave][g*CDIM + hl*4];
            atomicAdd(dst + 0, b0);
            atomicAdd(dst + 1, b1);
            atomicAdd(dst + 2, b2);
            atomicAdd(dst + 3, b3);
            if (hl == 0) {
                atomicAdd(&gcnt[wave][g], 1.0f);
                atomicAdd(&gsq [wave][g], ss*inv*inv);   // == sum(f*f) for this row
            }
        }
    }
    __syncthreads();

    // Block-level reduce of the 4 wave copies, un-swizzle, write partial slot.
    float* out = partial + (size_t)blockIdx.x * SLOT;
    for (int e = tid; e < GNUM*CDIM; e += 256) {
        const int g = e >> 7;
        const int s = e & 127;                              // storage index in group
        const int c = (s & ~3) | ((s & 3) ^ ((s >> 5) & 3)); // logical channel
        out[g*CDIM + c] = gsum[0][e] + gsum[1][e] + gsum[2][e] + gsum[3][e];
    }
    if (tid < GNUM) {
        out[GNUM*CDIM + tid]        = gcnt[0][tid] + gcnt[1][tid] + gcnt[2][tid] + gcnt[3][tid];
        out[GNUM*CDIM + GNUM + tid] = gsq [0][tid] + gsq [1][tid] + gsq [2][tid] + gsq [3][tid];
    }
}

// ---------------- Kernel 2: parallel column reduction of partial slots ----------------
__global__ __launch_bounds__(256)
void oc_reduce(const float* __restrict__ partial, float* __restrict__ finalv, int nb)
{
    __shared__ float sdata[256];
    const int e     = blockIdx.x*64 + (threadIdx.x & 63);
    const int blane = threadIdx.x >> 6;
    float acc = 0.f;
    if (e < SLOT)
        for (int b = blane; b < nb; b += 4)
            acc += partial[(size_t)b*SLOT + e];
    sdata[threadIdx.x] = acc;
    __syncthreads();
    if (threadIdx.x < 64 && e < SLOT)
        finalv[e] = sdata[threadIdx.x] + sdata[threadIdx.x + 64]
                  + sdata[threadIdx.x + 128] + sdata[threadIdx.x + 192];
}

// ---------------- Kernel 3: remap/compact + loss ----------------
__global__ __launch_bounds__(256)
void oc_loss(const float* __restrict__ fin, float* __restrict__ out)
{
    __shared__ float M[GNUM][CDIM];
    __shared__ float MS[GNUM];
    __shared__ float Cs[GNUM];
    __shared__ int   srcmap[GNUM];
    __shared__ int   Ush;
    __shared__ float red[4];

    const int tid = threadIdx.x;
    if (tid < GNUM) Cs[tid] = fin[GNUM*CDIM + tid];
    __syncthreads();

    if (tid == 0) {
        int u = 0;
        for (int g = 0; g < GNUM; ++g)
            if (Cs[g] > 0.f) srcmap[u++] = g;
        Ush = u;
        for (int k = u; k < GNUM; ++k) srcmap[k] = -1;
    }
    __syncthreads();
    const int U = Ush;

    for (int e = tid; e < GNUM*CDIM; e += 256) {
        const int u = e >> 7, c = e & 127;
        const int g = srcmap[u];
        M[u][c] = (g >= 0) ? fin[g*CDIM + c] / fmaxf(Cs[g], 1.f) : 0.f;
    }
    if (tid < GNUM) {
        const int g = srcmap[tid];
        MS[tid] = (g >= 0) ? fin[GNUM*CDIM + GNUM + g] / fmaxf(Cs[g], 1.f) : 0.f;
    }
    __syncthreads();

    float acc = 0.f;
    for (int e = tid; e < (GNUM-2)*CDIM; e += 256) {
        const int i = e >> 7, c = e & 127;
        if (i + 2 < U) {
            const float m1 = M[i][c], m2 = M[i+1][c], m3 = M[i+2][c];
            acc += m2*(m1 + m3) - m1*m3;
        }
    }
    acc += __shfl_xor(acc, 1);
    acc += __shfl_xor(acc, 2);
    acc += __shfl_xor(acc, 4);
    acc += __shfl_xor(acc, 8);
    acc += __shfl_xor(acc, 16);
    acc += __shfl_xor(acc, 32);
    if ((tid & 63) == 0) red[tid >> 6] = acc;
    __syncthreads();

    if (tid == 0) {
        float tot = red[0] + red[1] + red[2] + red[3];
        for (int i = 0; i < GNUM-2; ++i)
            if (i + 2 < U) tot -= MS[i+1];
        out[0] = tot / (float)(U - 2);
    }
}

extern "C" void kernel_launch(void* const* d_in, const int* in_sizes, int n_in,
                              void* d_out, int out_size, void* d_ws, size_t ws_size,
                              hipStream_t stream) {
    const float* feat   = (const float*)d_in[0];
    const int*   scores = (const int*)d_in[1];
    float*       out    = (float*)d_out;

    const int B      = in_sizes[1];          // number of rows (scores count)
    const int npairs = (B + 1) / 2;

    // ws layout: [nb * SLOT] partial slots, then [SLOT] final vector.
    long long cap = (long long)(ws_size / (SLOT * sizeof(float))) - 1;
    int nb = (int)(cap < 1 ? 1 : (cap > NBMAX ? NBMAX : cap));

    float* partial = (float*)d_ws;
    float* finalv  = partial + (size_t)nb * SLOT;

    hipLaunchKernelGGL(oc_accum,  dim3(nb), dim3(256), 0, stream, feat, scores, partial, B, npairs);
    hipLaunchKernelGGL(oc_reduce, dim3((SLOT + 63) / 64), dim3(256), 0, stream, partial, finalv, nb);
    hipLaunchKernelGGL(oc_loss,   dim3(1), dim3(256), 0, stream, finalv, out);
}

// Round 2
// 94.547 us; speedup vs baseline: 4.6159x; 4.6159x over previous
//
#include <hip/hip_runtime.h>
#include <math.h>

#define GNUM 16
#define CDIM 128
#define SLOT (GNUM*CDIM + 2*GNUM)   // 2080 floats per partial slot
#define NBMAX 1024
#define NRSL 8                       // row-slices for the K2 reduction

// ---------------- Kernel 1: normalize + register-resident segment accumulate ----------------
// 256 threads = 4 waves. Each wave handles 2 rows per pair-index p:
//   lane loads float4 at pair-base + lane*16B -> lanes 0-31 = row 2p, lanes 32-63 = row 2p+1.
// NO LDS and NO atomics in the hot loop: each lane keeps float4 acc[16] in VGPRs
// (compile-time indices only), selected per group via cndmask+fma.
// cnt/sq: lane hl accumulates the scalar stats for group g == hl (2 VGPRs).
__global__ __launch_bounds__(256, 4)
void oc_accum(const float* __restrict__ feat, const int* __restrict__ scores,
              float* __restrict__ partial, int B, int npairs)
{
    __shared__ float ws_sum[4][GNUM][CDIM];   // 32 KB, epilogue only
    __shared__ float ws_cnt[4][GNUM];
    __shared__ float ws_sq [4][GNUM];

    const int tid  = threadIdx.x;
    const int wave = tid >> 6;
    const int lane = tid & 63;
    const int hl   = lane & 31;       // lane within half-wave (channel block hl*4..hl*4+3)
    const int half = lane >> 5;       // which row of the pair

    float4 acc[GNUM];
    #pragma unroll
    for (int gg = 0; gg < GNUM; ++gg) acc[gg] = make_float4(0.f, 0.f, 0.f, 0.f);
    float cnt = 0.f, sq = 0.f;

    const int gw = blockIdx.x*4 + wave;
    const int nw = gridDim.x*4;

    auto process = [&](float4 x, int g) {
        float ss = x.x*x.x + x.y*x.y + x.z*x.z + x.w*x.w;
        ss += __shfl_xor(ss, 1);
        ss += __shfl_xor(ss, 2);
        ss += __shfl_xor(ss, 4);
        ss += __shfl_xor(ss, 8);
        ss += __shfl_xor(ss, 16);           // masks <32 never cross the half boundary
        const float inv = 1.0f / fmaxf(sqrtf(ss), 1e-12f);
        #pragma unroll
        for (int gg = 0; gg < GNUM; ++gg) {
            const float w = (g == gg) ? inv : 0.0f;
            acc[gg].x = fmaf(x.x, w, acc[gg].x);
            acc[gg].y = fmaf(x.y, w, acc[gg].y);
            acc[gg].z = fmaf(x.z, w, acc[gg].z);
            acc[gg].w = fmaf(x.w, w, acc[gg].w);
        }
        if (g == hl) { cnt += 1.0f; sq += ss*inv*inv; }
    };

    for (int p = gw; p < npairs; p += 2*nw) {
        const int pB = p + nw;
        const bool hasB = (pB < npairs);    // wave-uniform

        const int ra = 2*p + half;
        float4 xa = make_float4(0.f,0.f,0.f,0.f);
        int ga = -1;
        if (ra < B) {
            xa = *reinterpret_cast<const float4*>(feat + (size_t)p*(2*CDIM) + (size_t)lane*4);
            ga = scores[ra];
        }
        float4 xb = make_float4(0.f,0.f,0.f,0.f);
        int gb = -1;
        if (hasB) {
            const int rb = 2*pB + half;
            if (rb < B) {
                xb = *reinterpret_cast<const float4*>(feat + (size_t)pB*(2*CDIM) + (size_t)lane*4);
                gb = scores[rb];
            }
        }

        process(xa, ga);
        if (hasB) process(xb, gb);
    }

    // combine the two halves of the wave in-register
    #pragma unroll
    for (int gg = 0; gg < GNUM; ++gg) {
        acc[gg].x += __shfl_xor(acc[gg].x, 32);
        acc[gg].y += __shfl_xor(acc[gg].y, 32);
        acc[gg].z += __shfl_xor(acc[gg].z, 32);
        acc[gg].w += __shfl_xor(acc[gg].w, 32);
    }
    cnt += __shfl_xor(cnt, 32);
    sq  += __shfl_xor(sq, 32);

    // direct (non-RMW) per-wave LDS stores
    if (half == 0) {
        #pragma unroll
        for (int gg = 0; gg < GNUM; ++gg)
            *reinterpret_cast<float4*>(&ws_sum[wave][gg][hl*4]) = acc[gg];
        if (hl < GNUM) { ws_cnt[wave][hl] = cnt; ws_sq[wave][hl] = sq; }
    }
    __syncthreads();

    // block-level reduce of the 4 wave copies, write partial slot
    float* out = partial + (size_t)blockIdx.x * SLOT;
    const float* f0 = &ws_sum[0][0][0];
    const float* f1 = &ws_sum[1][0][0];
    const float* f2 = &ws_sum[2][0][0];
    const float* f3 = &ws_sum[3][0][0];
    for (int e = tid; e < GNUM*CDIM; e += 256)
        out[e] = f0[e] + f1[e] + f2[e] + f3[e];
    if (tid < GNUM) {
        out[GNUM*CDIM + tid]        = ws_cnt[0][tid] + ws_cnt[1][tid] + ws_cnt[2][tid] + ws_cnt[3][tid];
        out[GNUM*CDIM + GNUM + tid] = ws_sq [0][tid] + ws_sq [1][tid] + ws_sq [2][tid] + ws_sq [3][tid];
    }
}

// ---------------- Kernel 2: parallel column reduction of partial slots ----------------
// grid (ceil(SLOT/64), NRSL): blockIdx.y picks a row-slice; output NRSL partial vectors.
__global__ __launch_bounds__(256)
void oc_reduce(const float* __restrict__ partial, float* __restrict__ fin8, int nb)
{
    __shared__ float sdata[256];
    const int e     = blockIdx.x*64 + (threadIdx.x & 63);
    const int blane = threadIdx.x >> 6;
    float acc = 0.f;
    if (e < SLOT)
        for (int b = blockIdx.y + blane*NRSL; b < nb; b += 4*NRSL)
            acc += partial[(size_t)b*SLOT + e];
    sdata[threadIdx.x] = acc;
    __syncthreads();
    if (threadIdx.x < 64 && e < SLOT)
        fin8[(size_t)blockIdx.y*SLOT + e] =
            sdata[threadIdx.x] + sdata[threadIdx.x + 64] +
            sdata[threadIdx.x + 128] + sdata[threadIdx.x + 192];
}

// ---------------- Kernel 3: sum slices + remap/compact + loss ----------------
__global__ __launch_bounds__(256)
void oc_loss(const float* __restrict__ fin8, float* __restrict__ out)
{
    __shared__ float FIN[SLOT];
    __shared__ float M[GNUM][CDIM];
    __shared__ float MS[GNUM];
    __shared__ float Cs[GNUM];
    __shared__ int   srcmap[GNUM];
    __shared__ int   Ush;
    __shared__ float red[4];

    const int tid = threadIdx.x;

    for (int e = tid; e < SLOT; e += 256) {
        float a = 0.f;
        #pragma unroll
        for (int r = 0; r < NRSL; ++r) a += fin8[(size_t)r*SLOT + e];
        FIN[e] = a;
    }
    __syncthreads();

    if (tid < GNUM) Cs[tid] = FIN[GNUM*CDIM + tid];
    __syncthreads();

    if (tid == 0) {
        int u = 0;
        for (int g = 0; g < GNUM; ++g)
            if (Cs[g] > 0.f) srcmap[u++] = g;
        Ush = u;
        for (int k = u; k < GNUM; ++k) srcmap[k] = -1;
    }
    __syncthreads();
    const int U = Ush;

    for (int e = tid; e < GNUM*CDIM; e += 256) {
        const int u = e >> 7, c = e & 127;
        const int g = srcmap[u];
        M[u][c] = (g >= 0) ? FIN[g*CDIM + c] / fmaxf(Cs[g], 1.f) : 0.f;
    }
    if (tid < GNUM) {
        const int g = srcmap[tid];
        MS[tid] = (g >= 0) ? FIN[GNUM*CDIM + GNUM + g] / fmaxf(Cs[g], 1.f) : 0.f;
    }
    __syncthreads();

    float acc = 0.f;
    for (int e = tid; e < (GNUM-2)*CDIM; e += 256) {
        const int i = e >> 7, c = e & 127;
        if (i + 2 < U) {
            const float m1 = M[i][c], m2 = M[i+1][c], m3 = M[i+2][c];
            acc += m2*(m1 + m3) - m1*m3;
        }
    }
    acc += __shfl_xor(acc, 1);
    acc += __shfl_xor(acc, 2);
    acc += __shfl_xor(acc, 4);
    acc += __shfl_xor(acc, 8);
    acc += __shfl_xor(acc, 16);
    acc += __shfl_xor(acc, 32);
    if ((tid & 63) == 0) red[tid >> 6] = acc;
    __syncthreads();

    if (tid == 0) {
        float tot = red[0] + red[1] + red[2] + red[3];
        for (int i = 0; i < GNUM-2; ++i)
            if (i + 2 < U) tot -= MS[i+1];
        out[0] = tot / (float)(U - 2);
    }
}

extern "C" void kernel_launch(void* const* d_in, const int* in_sizes, int n_in,
                              void* d_out, int out_size, void* d_ws, size_t ws_size,
                              hipStream_t stream) {
    const float* feat   = (const float*)d_in[0];
    const int*   scores = (const int*)d_in[1];
    float*       out    = (float*)d_out;

    const int B      = in_sizes[1];          // number of rows
    const int npairs = (B + 1) / 2;

    // ws layout: [nb * SLOT] partial slots, then [NRSL * SLOT] slice vectors.
    long long cap = (long long)(ws_size / (SLOT * sizeof(float))) - NRSL;
    int nb = (int)(cap < 1 ? 1 : (cap > NBMAX ? NBMAX : cap));

    float* partial = (float*)d_ws;
    float* fin8    = partial + (size_t)nb * SLOT;

    hipLaunchKernelGGL(oc_accum,  dim3(nb), dim3(256), 0, stream, feat, scores, partial, B, npairs);
    hipLaunchKernelGGL(oc_reduce, dim3((SLOT + 63) / 64, NRSL), dim3(256), 0, stream, partial, fin8, nb);
    hipLaunchKernelGGL(oc_loss,   dim3(1), dim3(256), 0, stream, fin8, out);
}

// Round 3
// 84.244 us; speedup vs baseline: 5.1804x; 1.1223x over previous
//
#include <hip/hip_runtime.h>
#include <math.h>

#define GNUM 16
#define CDIM 128
#define SLOT (GNUM*CDIM + 2*GNUM)   // 2080 floats per partial slot
#define NBMAX 1024
#define NRSL 8                       // row-slices for the K2 reduction

typedef float v2f __attribute__((ext_vector_type(2)));

// ---------------- Kernel 1: normalize + register-resident segment accumulate ----------------
// 256 threads = 4 waves. Each wave owns a CONTIGUOUS chunk of row-pairs.
// Per pair p: lane loads float4 at pair-base + lane*16B -> lanes 0-31 = row 2p,
// lanes 32-63 = row 2p+1. No LDS / no atomics in the hot loop: each lane keeps
// v2f acc[16][2] in VGPRs (compile-time indices), accumulated via cndmask + v_pk_fma_f32.
// Depth-2 software pipeline: pair i+1's loads issue before processing pair i.
__global__ __launch_bounds__(256, 4)
void oc_accum(const float* __restrict__ feat, const int* __restrict__ scores,
              float* __restrict__ partial, int B, int npairs)
{
    __shared__ float ws_sum[4][GNUM][CDIM];   // 32 KB, epilogue only
    __shared__ float ws_cnt[4][GNUM];
    __shared__ float ws_sq [4][GNUM];

    const int tid  = threadIdx.x;
    const int wave = tid >> 6;
    const int lane = tid & 63;
    const int hl   = lane & 31;       // lane within half-wave (channels hl*4..hl*4+3)
    const int half = lane >> 5;       // which row of the pair

    v2f acc[GNUM][2];
    #pragma unroll
    for (int gg = 0; gg < GNUM; ++gg) { acc[gg][0] = (v2f)0.f; acc[gg][1] = (v2f)0.f; }
    float cnt = 0.f, sq = 0.f;

    const int gw = blockIdx.x*4 + wave;
    const int nw = gridDim.x*4;

    // contiguous balanced chunks
    const int base = npairs / nw;
    const int rem  = npairs % nw;
    const int pbeg = gw * base + (gw < rem ? gw : rem);
    const int pcnt = base + (gw < rem ? 1 : 0);

    auto process = [&](float4 x, int g) {
        float ss = x.x*x.x + x.y*x.y + x.z*x.z + x.w*x.w;
        ss += __shfl_xor(ss, 1);
        ss += __shfl_xor(ss, 2);
        ss += __shfl_xor(ss, 4);
        ss += __shfl_xor(ss, 8);
        ss += __shfl_xor(ss, 16);           // masks <32 never cross the half boundary
        // inv = 1/max(sqrt(ss),1e-12): rsqrt for ss > 1e-24, else 1e12 (matches ref; x*1e12)
        const float inv = (ss > 1e-24f) ? rsqrtf(ss) : 1e12f;
        const v2f xlo = {x.x, x.y};
        const v2f xhi = {x.z, x.w};
        #pragma unroll
        for (int gg = 0; gg < GNUM; ++gg) {
            const float w = (g == gg) ? inv : 0.0f;
            const v2f wv = {w, w};
            acc[gg][0] = xlo * wv + acc[gg][0];   // v_pk_fma_f32
            acc[gg][1] = xhi * wv + acc[gg][1];
        }
        if (g == hl) { cnt += 1.0f; sq += ss*inv*inv; }
    };

    const float4* src = reinterpret_cast<const float4*>(feat) + (size_t)pbeg*32 + lane;

    float4 x = make_float4(0.f,0.f,0.f,0.f);
    int g = -1;
    if (pcnt > 0) { x = src[0]; g = scores[2*pbeg + half]; }
    #pragma unroll 2
    for (int i = 0; i < pcnt; ++i) {
        float4 xn = make_float4(0.f,0.f,0.f,0.f);
        int gn = -1;
        if (i + 1 < pcnt) {                 // wave-uniform
            xn = src[(size_t)(i+1)*32];
            gn = scores[2*(pbeg+i+1) + half];
        }
        process(x, g);
        x = xn; g = gn;
    }

    // odd B: the unpaired last row, handled once by wave 0 (half1 lanes contribute nothing)
    if ((B & 1) && gw == 0) {
        float4 xo = make_float4(0.f,0.f,0.f,0.f);
        int go = -1;
        if (half == 0) {
            xo = *(reinterpret_cast<const float4*>(feat) + (size_t)(B-1)*32 + hl);
            go = scores[B-1];
        }
        process(xo, go);
    }

    // combine the two halves of the wave in-register
    #pragma unroll
    for (int gg = 0; gg < GNUM; ++gg) {
        acc[gg][0].x += __shfl_xor(acc[gg][0].x, 32);
        acc[gg][0].y += __shfl_xor(acc[gg][0].y, 32);
        acc[gg][1].x += __shfl_xor(acc[gg][1].x, 32);
        acc[gg][1].y += __shfl_xor(acc[gg][1].y, 32);
    }
    cnt += __shfl_xor(cnt, 32);
    sq  += __shfl_xor(sq, 32);

    // direct (non-RMW) per-wave LDS stores
    if (half == 0) {
        #pragma unroll
        for (int gg = 0; gg < GNUM; ++gg) {
            *reinterpret_cast<v2f*>(&ws_sum[wave][gg][hl*4])     = acc[gg][0];
            *reinterpret_cast<v2f*>(&ws_sum[wave][gg][hl*4 + 2]) = acc[gg][1];
        }
        if (hl < GNUM) { ws_cnt[wave][hl] = cnt; ws_sq[wave][hl] = sq; }
    }
    __syncthreads();

    // block-level reduce of the 4 wave copies, write partial slot
    float* out = partial + (size_t)blockIdx.x * SLOT;
    const float* f0 = &ws_sum[0][0][0];
    const float* f1 = &ws_sum[1][0][0];
    const float* f2 = &ws_sum[2][0][0];
    const float* f3 = &ws_sum[3][0][0];
    for (int e = tid; e < GNUM*CDIM; e += 256)
        out[e] = f0[e] + f1[e] + f2[e] + f3[e];
    if (tid < GNUM) {
        out[GNUM*CDIM + tid]        = ws_cnt[0][tid] + ws_cnt[1][tid] + ws_cnt[2][tid] + ws_cnt[3][tid];
        out[GNUM*CDIM + GNUM + tid] = ws_sq [0][tid] + ws_sq [1][tid] + ws_sq [2][tid] + ws_sq [3][tid];
    }
}

// ---------------- Kernel 2: parallel column reduction of partial slots ----------------
// grid (ceil(SLOT/64), NRSL): blockIdx.y picks a row-slice; output NRSL partial vectors.
__global__ __launch_bounds__(256)
void oc_reduce(const float* __restrict__ partial, float* __restrict__ fin8, int nb)
{
    __shared__ float sdata[256];
    const int e     = blockIdx.x*64 + (threadIdx.x & 63);
    const int blane = threadIdx.x >> 6;
    float acc = 0.f;
    if (e < SLOT)
        for (int b = blockIdx.y + blane*NRSL; b < nb; b += 4*NRSL)
            acc += partial[(size_t)b*SLOT + e];
    sdata[threadIdx.x] = acc;
    __syncthreads();
    if (threadIdx.x < 64 && e < SLOT)
        fin8[(size_t)blockIdx.y*SLOT + e] =
            sdata[threadIdx.x] + sdata[threadIdx.x + 64] +
            sdata[threadIdx.x + 128] + sdata[threadIdx.x + 192];
}

// ---------------- Kernel 3: sum slices + remap/compact + loss ----------------
__global__ __launch_bounds__(256)
void oc_loss(const float* __restrict__ fin8, float* __restrict__ out)
{
    __shared__ float FIN[SLOT];
    __shared__ float M[GNUM][CDIM];
    __shared__ float MS[GNUM];
    __shared__ float Cs[GNUM];
    __shared__ int   srcmap[GNUM];
    __shared__ int   Ush;
    __shared__ float red[4];

    const int tid = threadIdx.x;

    for (int e = tid; e < SLOT; e += 256) {
        float a = 0.f;
        #pragma unroll
        for (int r = 0; r < NRSL; ++r) a += fin8[(size_t)r*SLOT + e];
        FIN[e] = a;
    }
    __syncthreads();

    if (tid < GNUM) Cs[tid] = FIN[GNUM*CDIM + tid];
    __syncthreads();

    if (tid == 0) {
        int u = 0;
        for (int g = 0; g < GNUM; ++g)
            if (Cs[g] > 0.f) srcmap[u++] = g;
        Ush = u;
        for (int k = u; k < GNUM; ++k) srcmap[k] = -1;
    }
    __syncthreads();
    const int U = Ush;

    for (int e = tid; e < GNUM*CDIM; e += 256) {
        const int u = e >> 7, c = e & 127;
        const int g = srcmap[u];
        M[u][c] = (g >= 0) ? FIN[g*CDIM + c] / fmaxf(Cs[g], 1.f) : 0.f;
    }
    if (tid < GNUM) {
        const int g = srcmap[tid];
        MS[tid] = (g >= 0) ? FIN[GNUM*CDIM + GNUM + g] / fmaxf(Cs[g], 1.f) : 0.f;
    }
    __syncthreads();

    float acc = 0.f;
    for (int e = tid; e < (GNUM-2)*CDIM; e += 256) {
        const int i = e >> 7, c = e & 127;
        if (i + 2 < U) {
            const float m1 = M[i][c], m2 = M[i+1][c], m3 = M[i+2][c];
            acc += m2*(m1 + m3) - m1*m3;
        }
    }
    acc += __shfl_xor(acc, 1);
    acc += __shfl_xor(acc, 2);
    acc += __shfl_xor(acc, 4);
    acc += __shfl_xor(acc, 8);
    acc += __shfl_xor(acc, 16);
    acc += __shfl_xor(acc, 32);
    if ((tid & 63) == 0) red[tid >> 6] = acc;
    __syncthreads();

    if (tid == 0) {
        float tot = red[0] + red[1] + red[2] + red[3];
        for (int i = 0; i < GNUM-2; ++i)
            if (i + 2 < U) tot -= MS[i+1];
        out[0] = tot / (float)(U - 2);
    }
}

extern "C" void kernel_launch(void* const* d_in, const int* in_sizes, int n_in,
                              void* d_out, int out_size, void* d_ws, size_t ws_size,
                              hipStream_t stream) {
    const float* feat   = (const float*)d_in[0];
    const int*   scores = (const int*)d_in[1];
    float*       out    = (float*)d_out;

    const int B      = in_sizes[1];          // number of rows
    const int npairs = B / 2;                // full pairs (odd row handled in-kernel)

    // ws layout: [nb * SLOT] partial slots, then [NRSL * SLOT] slice vectors.
    long long cap = (long long)(ws_size / (SLOT * sizeof(float))) - NRSL;
    int nb = (int)(cap < 1 ? 1 : (cap > NBMAX ? NBMAX : cap));

    float* partial = (float*)d_ws;
    float* fin8    = partial + (size_t)nb * SLOT;

    hipLaunchKernelGGL(oc_accum,  dim3(nb), dim3(256), 0, stream, feat, scores, partial, B, npairs);
    hipLaunchKernelGGL(oc_reduce, dim3((SLOT + 63) / 64, NRSL), dim3(256), 0, stream, partial, fin8, nb);
    hipLaunchKernelGGL(oc_loss,   dim3(1), dim3(256), 0, stream, fin8, out);
}